// Round 1
// baseline (483.021 us; speedup 1.0000x reference)
//
#include <hip/hip_runtime.h>

#define K_DIM 4096
#define N_DIM 8192   // rows of x
#define M_DIM 4096   // rows of weight

typedef int v4i __attribute__((ext_vector_type(4)));

// ---------------- amax (max |v|) reduction ----------------
__global__ void amax_kernel(const float4* __restrict__ p, int n4,
                            unsigned* __restrict__ out) {
  int tid = blockIdx.x * blockDim.x + threadIdx.x;
  int stride = gridDim.x * blockDim.x;
  float m = 0.f;
  for (int i = tid; i < n4; i += stride) {
    float4 v = p[i];
    m = fmaxf(m, fmaxf(fmaxf(fabsf(v.x), fabsf(v.y)),
                       fmaxf(fabsf(v.z), fabsf(v.w))));
  }
#pragma unroll
  for (int off = 32; off > 0; off >>= 1)
    m = fmaxf(m, __shfl_down(m, off));
  __shared__ float sm[4];
  int lane = threadIdx.x & 63, w = threadIdx.x >> 6;
  if (lane == 0) sm[w] = m;
  __syncthreads();
  if (threadIdx.x == 0) {
    m = fmaxf(fmaxf(sm[0], sm[1]), fmaxf(sm[2], sm[3]));
    atomicMax(out, __float_as_uint(m));  // values >= 0: uint order == float order
  }
}

// ---------------- quantize fp32 -> int8 (packed 4/int) ----------------
__global__ void quant_kernel(const float4* __restrict__ in, int* __restrict__ out,
                             int n4, const unsigned* __restrict__ amax_bits) {
  float scale = 127.0f / __uint_as_float(*amax_bits);
  int tid = blockIdx.x * blockDim.x + threadIdx.x;
  int stride = gridDim.x * blockDim.x;
  for (int i = tid; i < n4; i += stride) {
    float4 v = in[i];
    int q0 = (int)fminf(fmaxf(rintf(v.x * scale), -127.f), 127.f);
    int q1 = (int)fminf(fmaxf(rintf(v.y * scale), -127.f), 127.f);
    int q2 = (int)fminf(fmaxf(rintf(v.z * scale), -127.f), 127.f);
    int q3 = (int)fminf(fmaxf(rintf(v.w * scale), -127.f), 127.f);
    unsigned packed = (unsigned)(q0 & 255) | ((unsigned)(q1 & 255) << 8) |
                      ((unsigned)(q2 & 255) << 16) | ((unsigned)(q3 & 255) << 24);
    out[i] = (int)packed;
  }
}

// ---------------- int8 GEMM: out = qx (N,K) * qw^T (K,M), dequant + bias ----
__device__ __forceinline__ void gld_lds16(const void* g, void* l) {
  __builtin_amdgcn_global_load_lds(
      (const __attribute__((address_space(1))) void*)g,
      (__attribute__((address_space(3))) void*)l, 16, 0, 0);
}

__global__ __launch_bounds__(256, 2) void gemm_i8(
    const signed char* __restrict__ A,   // qx  [N_DIM][K_DIM]
    const signed char* __restrict__ B,   // qw  [M_DIM][K_DIM]
    const float* __restrict__ bias,      // [M_DIM]
    float* __restrict__ out,             // [N_DIM][M_DIM]
    const unsigned* __restrict__ scal)   // [0]=amax_x bits [1]=amax_w bits
{
  __shared__ signed char la[128 * 64];   // 8 KB  A-tile, row-major [128][64]
  __shared__ signed char lb[128 * 64];   // 8 KB  B-tile

  const int tid = threadIdx.x;
  const int lane = tid & 63;
  const int w = tid >> 6;          // wave 0..3, arranged 2x2 over 128x128
  const int wr = (w & 1) * 64;     // wave row offset (A/x dim)
  const int wc = (w >> 1) * 64;    // wave col offset (B/w dim)
  const long r0 = (long)blockIdx.x * 128;
  const long c0 = (long)blockIdx.y * 128;

  // staging: 512 chunks of 16B per tile; thread covers chunk tid and tid+256
  const int srow = tid >> 2;          // 0..63
  const int scol = (tid & 3) * 16;    // 0/16/32/48
  const signed char* ga0 = A + (r0 + srow) * K_DIM + scol;
  const signed char* ga1 = A + (r0 + 64 + srow) * K_DIM + scol;
  const signed char* gb0 = B + (c0 + srow) * K_DIM + scol;
  const signed char* gb1 = B + (c0 + 64 + srow) * K_DIM + scol;
  signed char* la0 = la + tid * 16;
  signed char* la1 = la + 4096 + tid * 16;
  signed char* lb0 = lb + tid * 16;
  signed char* lb1 = lb + 4096 + tid * 16;

  v4i acc[4][4];
#pragma unroll
  for (int i = 0; i < 4; ++i)
#pragma unroll
    for (int j = 0; j < 4; ++j) acc[i][j] = (v4i){0, 0, 0, 0};

  const int fr = lane & 15;   // fragment row (m or n)
  const int fq = lane >> 4;   // k-quad: k-chunk = fq*16

  for (int k0 = 0; k0 < K_DIM; k0 += 64) {
    gld_lds16(ga0 + k0, la0);
    gld_lds16(ga1 + k0, la1);
    gld_lds16(gb0 + k0, lb0);
    gld_lds16(gb1 + k0, lb1);
    __syncthreads();  // drains vmcnt (global_load_lds) + barrier

    v4i av[4], bv[4];
#pragma unroll
    for (int i = 0; i < 4; ++i)
      av[i] = *(const v4i*)(la + (wr + i * 16 + fr) * 64 + fq * 16);
#pragma unroll
    for (int j = 0; j < 4; ++j)
      bv[j] = *(const v4i*)(lb + (wc + j * 16 + fr) * 64 + fq * 16);
#pragma unroll
    for (int i = 0; i < 4; ++i)
#pragma unroll
      for (int j = 0; j < 4; ++j)
        acc[i][j] = __builtin_amdgcn_mfma_i32_16x16x64_i8(av[i], bv[j],
                                                          acc[i][j], 0, 0, 0);
    __syncthreads();  // protect LDS before next stage
  }

  const float dq =
      (__uint_as_float(scal[0]) * __uint_as_float(scal[1])) / 16129.0f;
  float bs[4];
#pragma unroll
  for (int j = 0; j < 4; ++j) bs[j] = bias[c0 + wc + j * 16 + fr];

#pragma unroll
  for (int i = 0; i < 4; ++i) {
    const long rbase = r0 + wr + i * 16 + fq * 4;  // C/D row=(lane>>4)*4+reg
#pragma unroll
    for (int j = 0; j < 4; ++j) {
      const long c = c0 + wc + j * 16 + fr;        // C/D col=lane&15
#pragma unroll
      for (int t = 0; t < 4; ++t) {
        out[(rbase + t) * (long)M_DIM + c] = (float)acc[i][j][t] * dq + bs[j];
      }
    }
  }
}

extern "C" void kernel_launch(void* const* d_in, const int* in_sizes, int n_in,
                              void* d_out, int out_size, void* d_ws, size_t ws_size,
                              hipStream_t stream) {
  const float* x = (const float*)d_in[0];      // [8192,4096]
  const float* wt = (const float*)d_in[1];     // [4096,4096]
  const float* bias = (const float*)d_in[2];   // [4096]
  float* out = (float*)d_out;

  unsigned* scal = (unsigned*)d_ws;                       // 2 scalars
  signed char* qx = (signed char*)d_ws + 256;             // 32 MiB
  signed char* qw = qx + (long)N_DIM * K_DIM;             // 16 MiB

  hipMemsetAsync(d_ws, 0, 16, stream);  // zero amax slots (ws poisoned 0xAA)

  const int n4x = N_DIM * K_DIM / 4;   // 8388608
  const int n4w = M_DIM * K_DIM / 4;   // 4194304
  amax_kernel<<<2048, 256, 0, stream>>>((const float4*)x, n4x, scal + 0);
  amax_kernel<<<1024, 256, 0, stream>>>((const float4*)wt, n4w, scal + 1);
  quant_kernel<<<2048, 256, 0, stream>>>((const float4*)x, (int*)qx, n4x, scal + 0);
  quant_kernel<<<1024, 256, 0, stream>>>((const float4*)wt, (int*)qw, n4w, scal + 1);

  dim3 grid(N_DIM / 128, M_DIM / 128);  // 64 x 32
  gemm_i8<<<grid, 256, 0, stream>>>(qx, qw, bias, out, scal);
}

// Round 2
// 441.136 us; speedup vs baseline: 1.0949x; 1.0949x over previous
//
#include <hip/hip_runtime.h>

#define K_DIM 4096
#define N_DIM 8192   // rows of x
#define M_DIM 4096   // rows of weight

typedef int v4i __attribute__((ext_vector_type(4)));

// ---------------- fused amax over x and w ----------------
// blocks [0,2048) reduce x -> scal[0]; blocks [2048,3072) reduce w -> scal[1]
__global__ void amax2_kernel(const float4* __restrict__ x,
                             const float4* __restrict__ w,
                             unsigned* __restrict__ scal) {
  const int XB = 2048, WB = 1024;
  const float4* p;
  int n4, b, nb;
  unsigned* out;
  if (blockIdx.x < XB) {
    p = x; n4 = N_DIM * K_DIM / 4; out = scal + 0; b = blockIdx.x; nb = XB;
  } else {
    p = w; n4 = M_DIM * K_DIM / 4; out = scal + 1; b = blockIdx.x - XB; nb = WB;
  }
  int tid = b * blockDim.x + threadIdx.x;
  int stride = nb * blockDim.x;
  float m = 0.f;
  for (int i = tid; i < n4; i += stride) {
    float4 v = p[i];
    m = fmaxf(m, fmaxf(fmaxf(fabsf(v.x), fabsf(v.y)),
                       fmaxf(fabsf(v.z), fabsf(v.w))));
  }
#pragma unroll
  for (int off = 32; off > 0; off >>= 1)
    m = fmaxf(m, __shfl_down(m, off));
  __shared__ float sm[4];
  int lane = threadIdx.x & 63, wv = threadIdx.x >> 6;
  if (lane == 0) sm[wv] = m;
  __syncthreads();
  if (threadIdx.x == 0) {
    m = fmaxf(fmaxf(sm[0], sm[1]), fmaxf(sm[2], sm[3]));
    atomicMax(out, __float_as_uint(m));  // values >= 0: uint order == float order
  }
}

// ---------------- fused quantize fp32 -> int8, 16 elems/iter ----------------
__device__ __forceinline__ unsigned pack4(float4 v, float s) {
  int q0 = (int)fminf(fmaxf(rintf(v.x * s), -127.f), 127.f);
  int q1 = (int)fminf(fmaxf(rintf(v.y * s), -127.f), 127.f);
  int q2 = (int)fminf(fmaxf(rintf(v.z * s), -127.f), 127.f);
  int q3 = (int)fminf(fmaxf(rintf(v.w * s), -127.f), 127.f);
  return (unsigned)(q0 & 255) | ((unsigned)(q1 & 255) << 8) |
         ((unsigned)(q2 & 255) << 16) | ((unsigned)(q3 & 255) << 24);
}

__global__ void quant2_kernel(const float4* __restrict__ x,
                              const float4* __restrict__ w,
                              int4* __restrict__ qx, int4* __restrict__ qw,
                              const unsigned* __restrict__ scal) {
  const int XB = 2048, WB = 1024;
  const float4* in;
  int4* out;
  int n16, b, nb;
  float amax;
  if (blockIdx.x < XB) {
    in = x; out = qx; n16 = N_DIM * K_DIM / 16; b = blockIdx.x; nb = XB;
    amax = __uint_as_float(scal[0]);
  } else {
    in = w; out = qw; n16 = M_DIM * K_DIM / 16; b = blockIdx.x - XB; nb = WB;
    amax = __uint_as_float(scal[1]);
  }
  float s = 127.0f / amax;
  int tid = b * blockDim.x + threadIdx.x;
  int stride = nb * blockDim.x;
  for (int i = tid; i < n16; i += stride) {
    float4 v0 = in[4 * i + 0];
    float4 v1 = in[4 * i + 1];
    float4 v2 = in[4 * i + 2];
    float4 v3 = in[4 * i + 3];
    int4 o;
    o.x = (int)pack4(v0, s);
    o.y = (int)pack4(v1, s);
    o.z = (int)pack4(v2, s);
    o.w = (int)pack4(v3, s);
    out[i] = o;
  }
}

// ---------------- int8 GEMM: out = qx (N,K) * qw^T (K,M), dequant + bias ----
__device__ __forceinline__ void gld_lds16(const void* g, void* l) {
  __builtin_amdgcn_global_load_lds(
      (const __attribute__((address_space(1))) void*)g,
      (__attribute__((address_space(3))) void*)l, 16, 0, 0);
}

// 128x128 tile, BK=128, XOR-swizzled LDS (chunk c holds global chunk c^(row&7))
__global__ __launch_bounds__(256, 2) void gemm_i8(
    const signed char* __restrict__ A,   // qx  [N_DIM][K_DIM]
    const signed char* __restrict__ B,   // qw  [M_DIM][K_DIM]
    const float* __restrict__ bias,      // [M_DIM]
    float* __restrict__ out,             // [N_DIM][M_DIM]
    const unsigned* __restrict__ scal)   // [0]=amax_x bits [1]=amax_w bits
{
  __shared__ signed char la[128 * 128];  // 16 KB  A-tile [128 rows][128 k-bytes]
  __shared__ signed char lb[128 * 128];  // 16 KB  B-tile

  const int tid = threadIdx.x;
  const int lane = tid & 63;
  const int w = tid >> 6;          // wave 0..3, arranged 2x2 over 128x128
  const int wr = (w & 1) * 64;     // wave row offset (A/x dim)
  const int wc = (w >> 1) * 64;    // wave col offset (B/w dim)
  const long r0 = (long)blockIdx.x * 128;
  const long c0 = (long)blockIdx.y * 128;

  // staging: per pass p (0..3): row = p*32 + (tid>>3), LDS chunk = tid&7,
  // which must hold global chunk (tid&7) ^ (row&7); row&7 == (tid>>3)&7.
  const int srow = tid >> 3;                       // 0..31
  const int gcol = ((tid & 7) ^ (srow & 7)) * 16;  // swizzled source column
  const signed char* ga = A + (r0 + srow) * K_DIM + gcol;
  const signed char* gb = B + (c0 + srow) * K_DIM + gcol;

  v4i acc[4][4];
#pragma unroll
  for (int i = 0; i < 4; ++i)
#pragma unroll
    for (int j = 0; j < 4; ++j) acc[i][j] = (v4i){0, 0, 0, 0};

  const int fr = lane & 15;   // fragment row (m or n)
  const int fq = lane >> 4;   // k-quad
  const int sa = fr & 7;      // swizzle key for fragment reads

  for (int k0 = 0; k0 < K_DIM; k0 += 128) {
#pragma unroll
    for (int p = 0; p < 4; ++p) {
      gld_lds16(ga + (long)p * 32 * K_DIM + k0, la + p * 4096 + tid * 16);
      gld_lds16(gb + (long)p * 32 * K_DIM + k0, lb + p * 4096 + tid * 16);
    }
    __syncthreads();  // drains vmcnt (global_load_lds) + barrier

#pragma unroll
    for (int ks = 0; ks < 2; ++ks) {
      v4i av[4], bv[4];
#pragma unroll
      for (int i = 0; i < 4; ++i)
        av[i] = *(const v4i*)(la + (wr + i * 16 + fr) * 128 +
                              (((ks * 4 + fq) ^ sa) * 16));
#pragma unroll
      for (int j = 0; j < 4; ++j)
        bv[j] = *(const v4i*)(lb + (wc + j * 16 + fr) * 128 +
                              (((ks * 4 + fq) ^ sa) * 16));
#pragma unroll
      for (int i = 0; i < 4; ++i)
#pragma unroll
        for (int j = 0; j < 4; ++j)
          acc[i][j] = __builtin_amdgcn_mfma_i32_16x16x64_i8(av[i], bv[j],
                                                            acc[i][j], 0, 0, 0);
    }
    __syncthreads();  // protect LDS before next stage
  }

  const float dq =
      (__uint_as_float(scal[0]) * __uint_as_float(scal[1])) / 16129.0f;
  float bs[4];
#pragma unroll
  for (int j = 0; j < 4; ++j) bs[j] = bias[c0 + wc + j * 16 + fr];

#pragma unroll
  for (int i = 0; i < 4; ++i) {
    const long rbase = r0 + wr + i * 16 + fq * 4;  // C/D row=(lane>>4)*4+reg
#pragma unroll
    for (int j = 0; j < 4; ++j) {
      const long c = c0 + wc + j * 16 + fr;        // C/D col=lane&15
#pragma unroll
      for (int t = 0; t < 4; ++t) {
        out[(rbase + t) * (long)M_DIM + c] = (float)acc[i][j][t] * dq + bs[j];
      }
    }
  }
}

extern "C" void kernel_launch(void* const* d_in, const int* in_sizes, int n_in,
                              void* d_out, int out_size, void* d_ws, size_t ws_size,
                              hipStream_t stream) {
  const float* x = (const float*)d_in[0];      // [8192,4096]
  const float* wt = (const float*)d_in[1];     // [4096,4096]
  const float* bias = (const float*)d_in[2];   // [4096]
  float* out = (float*)d_out;

  unsigned* scal = (unsigned*)d_ws;                       // 2 scalars
  signed char* qx = (signed char*)d_ws + 256;             // 32 MiB
  signed char* qw = qx + (long)N_DIM * K_DIM;             // 16 MiB

  hipMemsetAsync(d_ws, 0, 16, stream);  // zero amax slots (ws poisoned 0xAA)

  amax2_kernel<<<3072, 256, 0, stream>>>((const float4*)x, (const float4*)wt,
                                         scal);
  quant2_kernel<<<3072, 256, 0, stream>>>((const float4*)x, (const float4*)wt,
                                          (int4*)qx, (int4*)qw, scal);

  dim3 grid(N_DIM / 128, M_DIM / 128);  // 64 x 32
  gemm_i8<<<grid, 256, 0, stream>>>(qx, qw, bias, out, scal);
}